// Round 1
// baseline (308.197 us; speedup 1.0000x reference)
//
#include <hip/hip_runtime.h>
#include <math.h>

#define LN_EPS 1e-5f
#define EPS_ATTN 1e-8f
#define SCALE 0.125f  // D^-0.5, D=64

// ---------------------------------------------------------------------------
// 64-lane butterfly sum
__device__ __forceinline__ float wave_reduce_add64(float v) {
#pragma unroll
  for (int m = 1; m <= 32; m <<= 1) v += __shfl_xor(v, m, 64);
  return v;
}

// ---------------------------------------------------------------------------
// From a slot row (value sl at lane=d), compute q = LN(slots)@wq+bq, then
// qk[e] = scale * sum_d q[d]*wk[e,d], qb = scale * q.bk.  One wave per row.
__device__ void slot_to_qk(int bi, float sl, int lane,
    const float* __restrict__ wq, const float* __restrict__ bq,
    const float* __restrict__ wk, const float* __restrict__ bk,
    const float* __restrict__ g_sl, const float* __restrict__ beta_sl,
    float* __restrict__ qk, float* __restrict__ qb, float* lds)
{
  float s  = wave_reduce_add64(sl);
  float s2 = wave_reduce_add64(sl * sl);
  float mean = s * (1.0f / 64.0f);
  float var  = s2 * (1.0f / 64.0f) - mean * mean;
  float rstd = rsqrtf(var + LN_EPS);
  float xs = (sl - mean) * rstd * g_sl[lane] + beta_sl[lane];
  __syncthreads();
  lds[lane] = xs;
  __syncthreads();
  float q = bq[lane];
#pragma unroll 8
  for (int e = 0; e < 64; ++e) q += lds[e] * wq[e * 64 + lane];
  __syncthreads();
  lds[lane] = q;
  __syncthreads();
  float qkl = 0.0f;
#pragma unroll 8
  for (int d = 0; d < 64; ++d) qkl += lds[d] * wk[lane * 64 + d];
  qk[bi * 64 + lane] = qkl * SCALE;
  float qbl = wave_reduce_add64(q * bk[lane]);
  if (lane == 0) qb[bi] = qbl * SCALE;
}

// ---------------------------------------------------------------------------
// Init: slots = mu + exp(log_sigma)*noise; zero accumulators; prep qk/qb.
// grid = 512 blocks (b*8+i), block = 64 threads (lane = d)
__global__ __launch_bounds__(64) void k_init(
    const float* __restrict__ noise, const float* __restrict__ mu,
    const float* __restrict__ lsig,
    const float* __restrict__ wq, const float* __restrict__ bq,
    const float* __restrict__ wk, const float* __restrict__ bk,
    const float* __restrict__ g_sl, const float* __restrict__ beta_sl,
    float* __restrict__ S_buf, float* __restrict__ qk, float* __restrict__ qb,
    float* __restrict__ acc, float* __restrict__ asum)
{
  __shared__ float lds[64];
  int bi = blockIdx.x;
  int lane = threadIdx.x;
  float sl = mu[lane] + expf(lsig[lane]) * noise[bi * 64 + lane];
  S_buf[bi * 64 + lane] = sl;
  acc[bi * 64 + lane] = 0.0f;
  if (lane == 0) asum[bi] = 0.0f;
  slot_to_qk(bi, sl, lane, wq, bq, wk, bk, g_sl, beta_sl, qk, qb, lds);
}

// ---------------------------------------------------------------------------
// Main streaming pass: for each input row n: LN inline, dots vs 8 slots,
// softmax over slots (+eps), accumulate acc[b,i,:] += p_i * x_ln and
// asum[b,i] += p_i.  grid = (16 chunks, 64 batches), block = 256.
// Each wave handles 4 rows/iter: lane group (lane>>4) = row, (lane&15)*4 = e.
__global__ __launch_bounds__(256) void k_main(
    const float* __restrict__ inputs,
    const float* __restrict__ g_in, const float* __restrict__ beta_in,
    const float* __restrict__ qk, const float* __restrict__ qb,
    float* __restrict__ acc, float* __restrict__ asum)
{
  __shared__ float lds_acc[4][512];
  __shared__ float lds_as[4][8];
  const int b = blockIdx.y;
  const int chunk = blockIdx.x;
  const int tid = threadIdx.x;
  const int lane = tid & 63;
  const int wave = tid >> 6;
  const int p = lane & 15;

  float4 g4  = ((const float4*)g_in)[p];
  float4 be4 = ((const float4*)beta_in)[p];
  float4 qkv[8];
  float qbv[8];
  const float4* qk4 = (const float4*)(qk + b * 512);
#pragma unroll
  for (int i = 0; i < 8; ++i) {
    qkv[i] = qk4[i * 16 + p];
    qbv[i] = qb[b * 8 + i];
  }

  float4 accl[8];
  float asl[8];
#pragma unroll
  for (int i = 0; i < 8; ++i) { accl[i] = make_float4(0.f, 0.f, 0.f, 0.f); asl[i] = 0.f; }

  const float4* in4 = (const float4*)(inputs + (size_t)b * 4096 * 64);
  const int n0 = chunk * 256;

  for (int it = 0; it < 16; ++it) {
    int rbase = n0 + it * 16 + wave * 4;  // this wave's 4 rows
    float4 xv = in4[rbase * 16 + lane];

    // LayerNorm over the row (64 elems across 16 lanes)
    float s  = xv.x + xv.y + xv.z + xv.w;
    float s2 = xv.x * xv.x + xv.y * xv.y + xv.z * xv.z + xv.w * xv.w;
#pragma unroll
    for (int m = 1; m <= 8; m <<= 1) {
      s  += __shfl_xor(s, m, 64);
      s2 += __shfl_xor(s2, m, 64);
    }
    float mean = s * 0.015625f;
    float var  = s2 * 0.015625f - mean * mean;
    float rstd = rsqrtf(var + LN_EPS);
    float4 xln;
    xln.x = (xv.x - mean) * rstd * g4.x + be4.x;
    xln.y = (xv.y - mean) * rstd * g4.y + be4.y;
    xln.z = (xv.z - mean) * rstd * g4.z + be4.z;
    xln.w = (xv.w - mean) * rstd * g4.w + be4.w;

    // dots vs 8 slots (qk already folded with scale)
    float dots[8];
#pragma unroll
    for (int i = 0; i < 8; ++i) {
      float d = xln.x * qkv[i].x + xln.y * qkv[i].y + xln.z * qkv[i].z + xln.w * qkv[i].w;
#pragma unroll
      for (int m = 1; m <= 8; m <<= 1) d += __shfl_xor(d, m, 64);
      dots[i] = d + qbv[i];
    }

    // softmax over slots + eps
    float mx = dots[0];
#pragma unroll
    for (int i = 1; i < 8; ++i) mx = fmaxf(mx, dots[i]);
    float pv[8];
    float ps = 0.0f;
#pragma unroll
    for (int i = 0; i < 8; ++i) { pv[i] = __expf(dots[i] - mx); ps += pv[i]; }
    float inv = __builtin_amdgcn_rcpf(ps);
#pragma unroll
    for (int i = 0; i < 8; ++i) {
      float pp = pv[i] * inv + EPS_ATTN;
      asl[i] += pp;
      accl[i].x += pp * xln.x;
      accl[i].y += pp * xln.y;
      accl[i].z += pp * xln.z;
      accl[i].w += pp * xln.w;
    }
  }

  // combine the 4 row-groups within the wave (lanes p, p+16, p+32, p+48
  // hold the same e positions)
#pragma unroll
  for (int i = 0; i < 8; ++i) {
#pragma unroll
    for (int m = 16; m <= 32; m <<= 1) {
      accl[i].x += __shfl_xor(accl[i].x, m, 64);
      accl[i].y += __shfl_xor(accl[i].y, m, 64);
      accl[i].z += __shfl_xor(accl[i].z, m, 64);
      accl[i].w += __shfl_xor(accl[i].w, m, 64);
      asl[i]    += __shfl_xor(asl[i], m, 64);
    }
  }

  if (lane < 16) {
    float4* dst = (float4*)lds_acc[wave];
#pragma unroll
    for (int i = 0; i < 8; ++i) dst[i * 16 + p] = accl[i];
  }
  if (lane == 0) {
#pragma unroll
    for (int i = 0; i < 8; ++i) lds_as[wave][i] = asl[i];
  }
  __syncthreads();

  for (int f = tid; f < 512; f += 256) {
    float ssum = lds_acc[0][f] + lds_acc[1][f] + lds_acc[2][f] + lds_acc[3][f];
    atomicAdd(&acc[b * 512 + f], ssum);
  }
  if (tid < 8) {
    float ssum = lds_as[0][tid] + lds_as[1][tid] + lds_as[2][tid] + lds_as[3][tid];
    atomicAdd(&asum[b * 8 + tid], ssum);
  }
}

// ---------------------------------------------------------------------------
// Per-slot update: updates = acc@wv/asum + bv; GRU; residual MLP; write new
// slots; zero accumulators; prep qk/qb for the next iteration.
// grid = 512 blocks (b*8+i), block = 64 (lane = d)
__global__ __launch_bounds__(64) void k_update(
    const float* __restrict__ S_in, float* __restrict__ S_out,
    float* __restrict__ acc, float* __restrict__ asum,
    const float* __restrict__ wv, const float* __restrict__ bv,
    const float* __restrict__ w_ih, const float* __restrict__ b_ih,
    const float* __restrict__ w_hh, const float* __restrict__ b_hh,
    const float* __restrict__ w1, const float* __restrict__ b1,
    const float* __restrict__ w2, const float* __restrict__ b2,
    const float* __restrict__ g_ff, const float* __restrict__ beta_ff,
    const float* __restrict__ wq, const float* __restrict__ bq,
    const float* __restrict__ wk, const float* __restrict__ bk,
    const float* __restrict__ g_sl, const float* __restrict__ beta_sl,
    float* __restrict__ qk, float* __restrict__ qb)
{
  __shared__ float lds[128];
  int bi = blockIdx.x;
  int lane = threadIdx.x;

  float inv_as = 1.0f / asum[bi];
  lds[lane] = acc[bi * 64 + lane] * inv_as;
  // zero accumulators for the next main pass
  acc[bi * 64 + lane] = 0.0f;
  if (lane == 0) asum[bi] = 0.0f;
  __syncthreads();

  // updates[d] = sum_e a[e]*wv[e,d] + bv[d]
  float upd = bv[lane];
#pragma unroll 8
  for (int e = 0; e < 64; ++e) upd += lds[e] * wv[e * 64 + lane];
  float sp = S_in[bi * 64 + lane];
  __syncthreads();
  lds[lane] = upd;
  lds[64 + lane] = sp;
  __syncthreads();

  // GRU gates (torch order r,z,n): gx = upd@w_ih+b_ih, gh = sp@w_hh+b_hh
  float gx_r = b_ih[lane], gx_z = b_ih[64 + lane], gx_n = b_ih[128 + lane];
  float gh_r = b_hh[lane], gh_z = b_hh[64 + lane], gh_n = b_hh[128 + lane];
#pragma unroll 4
  for (int e = 0; e < 64; ++e) {
    float u = lds[e], h = lds[64 + e];
    gx_r += u * w_ih[e * 192 + lane];
    gx_z += u * w_ih[e * 192 + 64 + lane];
    gx_n += u * w_ih[e * 192 + 128 + lane];
    gh_r += h * w_hh[e * 192 + lane];
    gh_z += h * w_hh[e * 192 + 64 + lane];
    gh_n += h * w_hh[e * 192 + 128 + lane];
  }
  float r  = 1.0f / (1.0f + __expf(-(gx_r + gh_r)));
  float z  = 1.0f / (1.0f + __expf(-(gx_z + gh_z)));
  float nw = tanhf(gx_n + r * gh_n);
  float sn = (1.0f - z) * nw + z * sp;

  // residual MLP: sn + relu(LN(sn)@w1+b1)@w2 + b2
  float s  = wave_reduce_add64(sn);
  float s2 = wave_reduce_add64(sn * sn);
  float mean = s * (1.0f / 64.0f);
  float var  = s2 * (1.0f / 64.0f) - mean * mean;
  float rstd = rsqrtf(var + LN_EPS);
  float ff = (sn - mean) * rstd * g_ff[lane] + beta_ff[lane];
  __syncthreads();
  lds[lane] = ff;
  __syncthreads();
  float h1 = b1[lane], h2 = b1[64 + lane];
#pragma unroll 8
  for (int e = 0; e < 64; ++e) {
    float f = lds[e];
    h1 += f * w1[e * 128 + lane];
    h2 += f * w1[e * 128 + 64 + lane];
  }
  h1 = fmaxf(h1, 0.0f);
  h2 = fmaxf(h2, 0.0f);
  __syncthreads();
  lds[lane] = h1;
  lds[64 + lane] = h2;
  __syncthreads();
  float o = sn + b2[lane];
#pragma unroll 8
  for (int t = 0; t < 128; ++t) o += lds[t] * w2[t * 64 + lane];

  S_out[bi * 64 + lane] = o;

  __syncthreads();
  slot_to_qk(bi, o, lane, wq, bq, wk, bk, g_sl, beta_sl, qk, qb, lds);
}

// ---------------------------------------------------------------------------
extern "C" void kernel_launch(void* const* d_in, const int* in_sizes, int n_in,
                              void* d_out, int out_size, void* d_ws, size_t ws_size,
                              hipStream_t stream) {
  const float* inputs  = (const float*)d_in[0];
  const float* noise   = (const float*)d_in[1];
  const float* mu      = (const float*)d_in[2];
  const float* lsig    = (const float*)d_in[3];
  const float* wq      = (const float*)d_in[4];
  const float* bq      = (const float*)d_in[5];
  const float* wk      = (const float*)d_in[6];
  const float* bk      = (const float*)d_in[7];
  const float* wv      = (const float*)d_in[8];
  const float* bv      = (const float*)d_in[9];
  const float* w_ih    = (const float*)d_in[10];
  const float* b_ih    = (const float*)d_in[11];
  const float* w_hh    = (const float*)d_in[12];
  const float* b_hh    = (const float*)d_in[13];
  const float* w1      = (const float*)d_in[14];
  const float* b1      = (const float*)d_in[15];
  const float* w2      = (const float*)d_in[16];
  const float* b2      = (const float*)d_in[17];
  const float* g_in    = (const float*)d_in[18];
  const float* beta_in = (const float*)d_in[19];
  const float* g_sl    = (const float*)d_in[20];
  const float* beta_sl = (const float*)d_in[21];
  const float* g_ff    = (const float*)d_in[22];
  const float* beta_ff = (const float*)d_in[23];

  float* S_buf = (float*)d_ws;        // [64*8*64]
  float* qk    = S_buf + 32768;       // [64*8*64]
  float* qb    = qk + 32768;          // [64*8]
  float* acc   = qb + 512;            // [64*8*64]
  float* asum  = acc + 32768;         // [64*8]
  float* out   = (float*)d_out;

  k_init<<<512, 64, 0, stream>>>(noise, mu, lsig, wq, bq, wk, bk, g_sl, beta_sl,
                                 S_buf, qk, qb, acc, asum);

  for (int t = 0; t < 3; ++t) {
    k_main<<<dim3(16, 64), 256, 0, stream>>>(inputs, g_in, beta_in, qk, qb, acc, asum);
    float* dst = (t == 2) ? out : S_buf;
    k_update<<<512, 64, 0, stream>>>(S_buf, dst, acc, asum, wv, bv,
                                     w_ih, b_ih, w_hh, b_hh, w1, b1, w2, b2,
                                     g_ff, beta_ff, wq, bq, wk, bk, g_sl, beta_sl,
                                     qk, qb);
  }
}

// Round 2
// 294.474 us; speedup vs baseline: 1.0466x; 1.0466x over previous
//
#include <hip/hip_runtime.h>
#include <math.h>

#define LN_EPS 1e-5f
#define EPS_ATTN 1e-8f
#define SCALE 0.125f  // D^-0.5, D=64

// ---------------------------------------------------------------------------
// 64-lane butterfly sum
__device__ __forceinline__ float wave_reduce_add64(float v) {
#pragma unroll
  for (int m = 1; m <= 32; m <<= 1) v += __shfl_xor(v, m, 64);
  return v;
}

// ---------------------------------------------------------------------------
// One-time prep: fold q-projection and k-projection into a single matrix.
//   M[t*64+d] = scale * sum_j wq[t,j] * wk[d,j]
//   cvec[d]   = scale * sum_j bq[j]  * wk[d,j]
//   uvec[t]   = scale * sum_j wq[t,j]* bk[j]
//   s0        = scale * sum_j bq[j]  * bk[j]
// grid = 16 blocks x 256 threads; each thread computes one M entry.
__global__ __launch_bounds__(256) void k_prep(
    const float* __restrict__ wq, const float* __restrict__ wk,
    const float* __restrict__ bq, const float* __restrict__ bk,
    float* __restrict__ M, float* __restrict__ cvec,
    float* __restrict__ uvec, float* __restrict__ s0v)
{
  __shared__ float wqs[64 * 64];
  __shared__ float wks[64 * 65];  // padded: bank = (d + j) % 32, conflict-free
  int tid = threadIdx.x;
  for (int i = tid; i < 4096; i += 256) wqs[i] = wq[i];
  for (int i = tid; i < 4096; i += 256) wks[(i >> 6) * 65 + (i & 63)] = wk[i];
  __syncthreads();

  int idx = blockIdx.x * 256 + tid;
  int t = idx >> 6, d = idx & 63;
  float a = 0.0f;
#pragma unroll 8
  for (int j = 0; j < 64; ++j) a += wqs[t * 64 + j] * wks[d * 65 + j];
  M[idx] = a * SCALE;

  if (blockIdx.x == 0) {
    if (tid < 64) {
      float cc = 0.0f;
#pragma unroll 8
      for (int j = 0; j < 64; ++j) cc += bq[j] * wks[tid * 65 + j];
      cvec[tid] = cc * SCALE;
    } else if (tid < 128) {
      int t2 = tid - 64;
      float uu = 0.0f;
#pragma unroll 8
      for (int j = 0; j < 64; ++j) uu += wqs[t2 * 64 + j] * bk[j];
      uvec[t2] = uu * SCALE;
    } else if (tid == 128) {
      float ss = 0.0f;
      for (int j = 0; j < 64; ++j) ss += bq[j] * bk[j];
      s0v[0] = ss * SCALE;
    }
  }
}

// ---------------------------------------------------------------------------
// 256-thread slot->qk: given per-lane slot value sl (replicated across the
// 4 waves), compute LN then qk[d] = c[d] + sum_t ln[t]*M[t*64+d] (4-way
// K-split through LDS) and qb = s0 + ln . u.
__device__ void slot_qk_256(int bi, float sl, int w, int lane,
    const float* __restrict__ M, const float* __restrict__ cvec,
    const float* __restrict__ uvec, const float* __restrict__ s0v,
    const float* __restrict__ g_sl, const float* __restrict__ beta_sl,
    float* __restrict__ qk, float* __restrict__ qb,
    float (*red)[64], float* vals)
{
  // LN replicated per-wave (each wave holds the full 64-vector at lane=d)
  float s  = wave_reduce_add64(sl);
  float s2 = wave_reduce_add64(sl * sl);
  float mean = s * (1.0f / 64.0f);
  float var  = s2 * (1.0f / 64.0f) - mean * mean;
  float rstd = rsqrtf(var + LN_EPS);
  float ln = (sl - mean) * rstd * g_sl[lane] + beta_sl[lane];

  __syncthreads();
  if (w == 0) vals[lane] = ln;
  __syncthreads();

  float p = 0.0f;
#pragma unroll
  for (int j = 0; j < 16; ++j) {
    int t = w * 16 + j;
    p += vals[t] * M[t * 64 + lane];
  }
  red[w][lane] = p;
  if (w == 0) {
    float pb = wave_reduce_add64(ln * uvec[lane]);
    if (lane == 0) qb[bi] = s0v[0] + pb;
  }
  __syncthreads();
  if (w == 0)
    qk[bi * 64 + lane] = cvec[lane] + red[0][lane] + red[1][lane] + red[2][lane] + red[3][lane];
}

// ---------------------------------------------------------------------------
// Init: slots = mu + exp(log_sigma)*noise; zero accumulators; prep qk/qb.
// grid = 512 blocks (b*8+i), block = 256
__global__ __launch_bounds__(256) void k_init(
    const float* __restrict__ noise, const float* __restrict__ mu,
    const float* __restrict__ lsig,
    const float* __restrict__ M, const float* __restrict__ cvec,
    const float* __restrict__ uvec, const float* __restrict__ s0v,
    const float* __restrict__ g_sl, const float* __restrict__ beta_sl,
    float* __restrict__ S_buf, float* __restrict__ qk, float* __restrict__ qb,
    float* __restrict__ acc, float* __restrict__ asum)
{
  __shared__ float vals[64];
  __shared__ float red[4][64];
  int bi = blockIdx.x;
  int tid = threadIdx.x, w = tid >> 6, lane = tid & 63;
  float sl = mu[lane] + __expf(lsig[lane]) * noise[bi * 64 + lane];  // replicated
  if (w == 0) {
    S_buf[bi * 64 + lane] = sl;
    acc[bi * 64 + lane] = 0.0f;
    if (lane == 0) asum[bi] = 0.0f;
  }
  slot_qk_256(bi, sl, w, lane, M, cvec, uvec, s0v, g_sl, beta_sl, qk, qb, red, vals);
}

// ---------------------------------------------------------------------------
// Main streaming pass. grid = (32 chunks, 64 batches), block = 256.
// Each wave handles 4 rows/iter: lane group (lane>>4) = row, (lane&15)*4 = e.
__global__ __launch_bounds__(256) void k_main(
    const float* __restrict__ inputs,
    const float* __restrict__ g_in, const float* __restrict__ beta_in,
    const float* __restrict__ qk, const float* __restrict__ qb,
    float* __restrict__ acc, float* __restrict__ asum)
{
  __shared__ float lds_acc[4][512];
  __shared__ float lds_as[4][8];
  const int b = blockIdx.y;
  const int chunk = blockIdx.x;
  const int tid = threadIdx.x;
  const int lane = tid & 63;
  const int wave = tid >> 6;
  const int p = lane & 15;

  float4 g4  = ((const float4*)g_in)[p];
  float4 be4 = ((const float4*)beta_in)[p];
  float4 qkv[8];
  float qbv[8];
  const float4* qk4 = (const float4*)(qk + b * 512);
#pragma unroll
  for (int i = 0; i < 8; ++i) {
    qkv[i] = qk4[i * 16 + p];
    qbv[i] = qb[b * 8 + i];
  }

  float4 accl[8];
  float asl[8];
#pragma unroll
  for (int i = 0; i < 8; ++i) { accl[i] = make_float4(0.f, 0.f, 0.f, 0.f); asl[i] = 0.f; }

  const float4* in4 = (const float4*)(inputs + (size_t)b * 4096 * 64);
  const int n0 = chunk * 128;

  for (int it = 0; it < 8; ++it) {
    int rbase = n0 + it * 16 + wave * 4;  // this wave's 4 rows
    float4 xv = in4[rbase * 16 + lane];

    // LayerNorm over the row (64 elems across 16 lanes)
    float s  = xv.x + xv.y + xv.z + xv.w;
    float s2 = xv.x * xv.x + xv.y * xv.y + xv.z * xv.z + xv.w * xv.w;
#pragma unroll
    for (int m = 1; m <= 8; m <<= 1) {
      s  += __shfl_xor(s, m, 64);
      s2 += __shfl_xor(s2, m, 64);
    }
    float mean = s * 0.015625f;
    float var  = s2 * 0.015625f - mean * mean;
    float rstd = rsqrtf(var + LN_EPS);
    float4 xln;
    xln.x = (xv.x - mean) * rstd * g4.x + be4.x;
    xln.y = (xv.y - mean) * rstd * g4.y + be4.y;
    xln.z = (xv.z - mean) * rstd * g4.z + be4.z;
    xln.w = (xv.w - mean) * rstd * g4.w + be4.w;

    // dots vs 8 slots (qk already folded with scale)
    float dots[8];
#pragma unroll
    for (int i = 0; i < 8; ++i) {
      float d = xln.x * qkv[i].x + xln.y * qkv[i].y + xln.z * qkv[i].z + xln.w * qkv[i].w;
#pragma unroll
      for (int m = 1; m <= 8; m <<= 1) d += __shfl_xor(d, m, 64);
      dots[i] = d + qbv[i];
    }

    // softmax over slots + eps
    float mx = dots[0];
#pragma unroll
    for (int i = 1; i < 8; ++i) mx = fmaxf(mx, dots[i]);
    float pv[8];
    float ps = 0.0f;
#pragma unroll
    for (int i = 0; i < 8; ++i) { pv[i] = __expf(dots[i] - mx); ps += pv[i]; }
    float inv = __builtin_amdgcn_rcpf(ps);
#pragma unroll
    for (int i = 0; i < 8; ++i) {
      float pp = pv[i] * inv + EPS_ATTN;
      asl[i] += pp;
      accl[i].x += pp * xln.x;
      accl[i].y += pp * xln.y;
      accl[i].z += pp * xln.z;
      accl[i].w += pp * xln.w;
    }
  }

  // combine the 4 row-groups within the wave
#pragma unroll
  for (int i = 0; i < 8; ++i) {
#pragma unroll
    for (int m = 16; m <= 32; m <<= 1) {
      accl[i].x += __shfl_xor(accl[i].x, m, 64);
      accl[i].y += __shfl_xor(accl[i].y, m, 64);
      accl[i].z += __shfl_xor(accl[i].z, m, 64);
      accl[i].w += __shfl_xor(accl[i].w, m, 64);
      asl[i]    += __shfl_xor(asl[i], m, 64);
    }
  }

  if (lane < 16) {
    float4* dst = (float4*)lds_acc[wave];
#pragma unroll
    for (int i = 0; i < 8; ++i) dst[i * 16 + p] = accl[i];
  }
  if (lane == 0) {
#pragma unroll
    for (int i = 0; i < 8; ++i) lds_as[wave][i] = asl[i];
  }
  __syncthreads();

  for (int f = tid; f < 512; f += 256) {
    float ssum = lds_acc[0][f] + lds_acc[1][f] + lds_acc[2][f] + lds_acc[3][f];
    atomicAdd(&acc[b * 512 + f], ssum);
  }
  if (tid < 8) {
    float ssum = lds_as[0][tid] + lds_as[1][tid] + lds_as[2][tid] + lds_as[3][tid];
    atomicAdd(&asum[b * 8 + tid], ssum);
  }
}

// ---------------------------------------------------------------------------
// Per-slot update with 256 threads / 4-way K-split.
// grid = 512 blocks (b*8+i), block = 256 (w = wave, lane = d)
__global__ __launch_bounds__(256) void k_update(
    const float* __restrict__ S_in, float* __restrict__ S_out,
    float* __restrict__ acc, float* __restrict__ asum,
    const float* __restrict__ wv, const float* __restrict__ bv,
    const float* __restrict__ w_ih, const float* __restrict__ b_ih,
    const float* __restrict__ w_hh, const float* __restrict__ b_hh,
    const float* __restrict__ w1, const float* __restrict__ b1,
    const float* __restrict__ w2, const float* __restrict__ b2,
    const float* __restrict__ g_ff, const float* __restrict__ beta_ff,
    const float* __restrict__ M, const float* __restrict__ cvec,
    const float* __restrict__ uvec, const float* __restrict__ s0v,
    const float* __restrict__ g_sl, const float* __restrict__ beta_sl,
    float* __restrict__ qk, float* __restrict__ qb)
{
  __shared__ float vals[128];
  __shared__ float red[6][4][64];
  float* redf = &red[0][0][0];
  int bi = blockIdx.x;
  int tid = threadIdx.x, w = tid >> 6, lane = tid & 63;

  if (tid < 64) {
    float inv = 1.0f / asum[bi];
    vals[tid] = acc[bi * 64 + tid] * inv;
    acc[bi * 64 + tid] = 0.0f;       // reset for next main pass
    if (tid == 0) asum[bi] = 0.0f;
  }
  float sp = S_in[bi * 64 + lane];
  __syncthreads();

  // updates[d] = a @ wv + bv  (4-way K-split)
  float pu = 0.0f;
#pragma unroll
  for (int j = 0; j < 16; ++j) {
    int e = w * 16 + j;
    pu += vals[e] * wv[e * 64 + lane];
  }
  red[0][w][lane] = pu;
  __syncthreads();
  float upd = bv[lane] + red[0][0][lane] + red[0][1][lane] + red[0][2][lane] + red[0][3][lane];
  __syncthreads();
  if (w == 0) { vals[lane] = upd; vals[64 + lane] = sp; }
  __syncthreads();

  // GRU gates: 6 matvecs, 4-way K-split each
  float pr = 0, pz = 0, pn = 0, qr = 0, qz = 0, qn = 0;
#pragma unroll 4
  for (int j = 0; j < 16; ++j) {
    int e = w * 16 + j;
    float uu = vals[e], hh = vals[64 + e];
    const float* wi = w_ih + e * 192;
    const float* wh = w_hh + e * 192;
    pr += uu * wi[lane]; pz += uu * wi[64 + lane]; pn += uu * wi[128 + lane];
    qr += hh * wh[lane]; qz += hh * wh[64 + lane]; qn += hh * wh[128 + lane];
  }
  red[0][w][lane] = pr; red[1][w][lane] = pz; red[2][w][lane] = pn;
  red[3][w][lane] = qr; red[4][w][lane] = qz; red[5][w][lane] = qn;
  __syncthreads();
  float gxr = b_ih[lane], gxz = b_ih[64 + lane], gxn = b_ih[128 + lane];
  float ghr = b_hh[lane], ghz = b_hh[64 + lane], ghn = b_hh[128 + lane];
#pragma unroll
  for (int k = 0; k < 4; ++k) {
    gxr += red[0][k][lane]; gxz += red[1][k][lane]; gxn += red[2][k][lane];
    ghr += red[3][k][lane]; ghz += red[4][k][lane]; ghn += red[5][k][lane];
  }
  float r  = 1.0f / (1.0f + __expf(-(gxr + ghr)));
  float z  = 1.0f / (1.0f + __expf(-(gxz + ghz)));
  float nw = tanhf(gxn + r * ghn);
  float sn = (1.0f - z) * nw + z * sp;   // replicated across waves

  // ff = LN(sn)  (per-wave butterfly, replicated)
  float s  = wave_reduce_add64(sn);
  float s2 = wave_reduce_add64(sn * sn);
  float mean = s * (1.0f / 64.0f);
  float var  = s2 * (1.0f / 64.0f) - mean * mean;
  float rstd = rsqrtf(var + LN_EPS);
  float ff = (sn - mean) * rstd * g_ff[lane] + beta_ff[lane];
  __syncthreads();
  if (w == 0) vals[lane] = ff;
  __syncthreads();

  // h = relu(ff @ w1 + b1): 128 outputs, 2-way K-split
  {
    int o = tid & 127, half = tid >> 7;
    float ph = 0.0f;
#pragma unroll 8
    for (int j = 0; j < 32; ++j) {
      int e = half * 32 + j;
      ph += vals[e] * w1[e * 128 + o];
    }
    redf[half * 128 + o] = ph;
  }
  __syncthreads();
  if (tid < 128)
    vals[tid] = fmaxf(b1[tid] + redf[tid] + redf[128 + tid], 0.0f);
  __syncthreads();

  // o = sn + h @ w2 + b2: 64 outputs, 4-way K-split over 128
  float po = 0.0f;
#pragma unroll 8
  for (int j = 0; j < 32; ++j) {
    int t = w * 32 + j;
    po += vals[t] * w2[t * 64 + lane];
  }
  __syncthreads();   // redf[0..255] consumed above; safe to overwrite
  red[0][w][lane] = po;
  __syncthreads();
  float o = sn + b2[lane] + red[0][0][lane] + red[0][1][lane] + red[0][2][lane] + red[0][3][lane];
  if (w == 0) S_out[bi * 64 + lane] = o;

  // qk/qb for the next iteration (o is replicated across waves)
  slot_qk_256(bi, o, w, lane, M, cvec, uvec, s0v, g_sl, beta_sl, qk, qb,
              (float(*)[64])redf, vals);
}

// ---------------------------------------------------------------------------
extern "C" void kernel_launch(void* const* d_in, const int* in_sizes, int n_in,
                              void* d_out, int out_size, void* d_ws, size_t ws_size,
                              hipStream_t stream) {
  const float* inputs  = (const float*)d_in[0];
  const float* noise   = (const float*)d_in[1];
  const float* mu      = (const float*)d_in[2];
  const float* lsig    = (const float*)d_in[3];
  const float* wq      = (const float*)d_in[4];
  const float* bq      = (const float*)d_in[5];
  const float* wk      = (const float*)d_in[6];
  const float* bk      = (const float*)d_in[7];
  const float* wv      = (const float*)d_in[8];
  const float* bv      = (const float*)d_in[9];
  const float* w_ih    = (const float*)d_in[10];
  const float* b_ih    = (const float*)d_in[11];
  const float* w_hh    = (const float*)d_in[12];
  const float* b_hh    = (const float*)d_in[13];
  const float* w1      = (const float*)d_in[14];
  const float* b1      = (const float*)d_in[15];
  const float* w2      = (const float*)d_in[16];
  const float* b2      = (const float*)d_in[17];
  const float* g_in    = (const float*)d_in[18];
  const float* beta_in = (const float*)d_in[19];
  const float* g_sl    = (const float*)d_in[20];
  const float* beta_sl = (const float*)d_in[21];
  const float* g_ff    = (const float*)d_in[22];
  const float* beta_ff = (const float*)d_in[23];

  float* S_buf = (float*)d_ws;        // [64*8*64]
  float* qk    = S_buf + 32768;       // [64*8*64]
  float* qb    = qk + 32768;          // [64*8]
  float* acc   = qb + 512;            // [64*8*64]
  float* asum  = acc + 32768;         // [64*8]
  float* M     = asum + 512;          // [64*64]
  float* cvec  = M + 4096;            // [64]
  float* uvec  = cvec + 64;           // [64]
  float* s0v   = uvec + 64;           // [1]
  float* out   = (float*)d_out;

  k_prep<<<16, 256, 0, stream>>>(wq, wk, bq, bk, M, cvec, uvec, s0v);
  k_init<<<512, 256, 0, stream>>>(noise, mu, lsig, M, cvec, uvec, s0v,
                                  g_sl, beta_sl, S_buf, qk, qb, acc, asum);

  for (int t = 0; t < 3; ++t) {
    k_main<<<dim3(32, 64), 256, 0, stream>>>(inputs, g_in, beta_in, qk, qb, acc, asum);
    float* dst = (t == 2) ? out : S_buf;
    k_update<<<512, 256, 0, stream>>>(S_buf, dst, acc, asum, wv, bv,
                                      w_ih, b_ih, w_hh, b_hh, w1, b1, w2, b2,
                                      g_ff, beta_ff, M, cvec, uvec, s0v,
                                      g_sl, beta_sl, qk, qb);
  }
}

// Round 4
// 252.717 us; speedup vs baseline: 1.2195x; 1.1652x over previous
//
#include <hip/hip_runtime.h>
#include <math.h>

#define LN_EPS 1e-5f
#define EPS_ATTN 1e-8f
#define SCALE 0.125f  // D^-0.5, D=64

// ---------------------------------------------------------------------------
// 64-lane butterfly sum (used only in cold per-slot code)
__device__ __forceinline__ float wave_reduce_add64(float v) {
#pragma unroll
  for (int m = 1; m <= 32; m <<= 1) v += __shfl_xor(v, m, 64);
  return v;
}

// 16-lane allreduce sum on the VALU pipe via DPP (no LDS-pipe traffic).
// quad_perm[1,0,3,2]=0xB1 (xor1), quad_perm[2,3,0,1]=0x4E (xor2),
// row_ror:4=0x124, row_ror:8=0x128 (rows are 16 lanes on CDNA).
__device__ __forceinline__ float red16(float v) {
  v += __int_as_float(__builtin_amdgcn_update_dpp(0, __float_as_int(v), 0xB1, 0xF, 0xF, true));
  v += __int_as_float(__builtin_amdgcn_update_dpp(0, __float_as_int(v), 0x4E, 0xF, 0xF, true));
  v += __int_as_float(__builtin_amdgcn_update_dpp(0, __float_as_int(v), 0x124, 0xF, 0xF, true));
  v += __int_as_float(__builtin_amdgcn_update_dpp(0, __float_as_int(v), 0x128, 0xF, 0xF, true));
  return v;
}

// ---------------------------------------------------------------------------
// One-time prep: fold q-projection and k-projection into a single matrix.
//   M[t*64+d] = scale * sum_j wq[t,j] * wk[d,j]
//   cvec[d]   = scale * sum_j bq[j]  * wk[d,j]
//   uvec[t]   = scale * sum_j wq[t,j]* bk[j]
//   s0        = scale * sum_j bq[j]  * bk[j]
__global__ __launch_bounds__(256) void k_prep(
    const float* __restrict__ wq, const float* __restrict__ wk,
    const float* __restrict__ bq, const float* __restrict__ bk,
    float* __restrict__ M, float* __restrict__ cvec,
    float* __restrict__ uvec, float* __restrict__ s0v)
{
  __shared__ float wqs[64 * 64];
  __shared__ float wks[64 * 65];
  int tid = threadIdx.x;
  for (int i = tid; i < 4096; i += 256) wqs[i] = wq[i];
  for (int i = tid; i < 4096; i += 256) wks[(i >> 6) * 65 + (i & 63)] = wk[i];
  __syncthreads();

  int idx = blockIdx.x * 256 + tid;
  int t = idx >> 6, d = idx & 63;
  float a = 0.0f;
#pragma unroll 8
  for (int j = 0; j < 64; ++j) a += wqs[t * 64 + j] * wks[d * 65 + j];
  M[idx] = a * SCALE;

  if (blockIdx.x == 0) {
    if (tid < 64) {
      float cc = 0.0f;
#pragma unroll 8
      for (int j = 0; j < 64; ++j) cc += bq[j] * wks[tid * 65 + j];
      cvec[tid] = cc * SCALE;
    } else if (tid < 128) {
      int t2 = tid - 64;
      float uu = 0.0f;
#pragma unroll 8
      for (int j = 0; j < 64; ++j) uu += wqs[t2 * 64 + j] * bk[j];
      uvec[t2] = uu * SCALE;
    } else if (tid == 128) {
      float ss = 0.0f;
      for (int j = 0; j < 64; ++j) ss += bq[j] * bk[j];
      s0v[0] = ss * SCALE;
    }
  }
}

// ---------------------------------------------------------------------------
// 256-thread slot->qk: given per-lane slot value sl (replicated across the
// 4 waves), compute LN then qk[d] = c[d] + sum_t ln[t]*M[t*64+d] (4-way
// K-split through LDS) and qb = s0 + ln . u.
__device__ void slot_qk_256(int bi, float sl, int w, int lane,
    const float* __restrict__ M, const float* __restrict__ cvec,
    const float* __restrict__ uvec, const float* __restrict__ s0v,
    const float* __restrict__ g_sl, const float* __restrict__ beta_sl,
    float* __restrict__ qk, float* __restrict__ qb,
    float (*red)[64], float* vals)
{
  float s  = wave_reduce_add64(sl);
  float s2 = wave_reduce_add64(sl * sl);
  float mean = s * (1.0f / 64.0f);
  float var  = s2 * (1.0f / 64.0f) - mean * mean;
  float rstd = rsqrtf(var + LN_EPS);
  float ln = (sl - mean) * rstd * g_sl[lane] + beta_sl[lane];

  __syncthreads();
  if (w == 0) vals[lane] = ln;
  __syncthreads();

  float p = 0.0f;
#pragma unroll
  for (int j = 0; j < 16; ++j) {
    int t = w * 16 + j;
    p += vals[t] * M[t * 64 + lane];
  }
  red[w][lane] = p;
  if (w == 0) {
    float pb = wave_reduce_add64(ln * uvec[lane]);
    if (lane == 0) qb[bi] = s0v[0] + pb;
  }
  __syncthreads();
  if (w == 0)
    qk[bi * 64 + lane] = cvec[lane] + red[0][lane] + red[1][lane] + red[2][lane] + red[3][lane];
}

// ---------------------------------------------------------------------------
// Init: slots = mu + exp(log_sigma)*noise; zero accumulators; prep qk/qb.
__global__ __launch_bounds__(256) void k_init(
    const float* __restrict__ noise, const float* __restrict__ mu,
    const float* __restrict__ lsig,
    const float* __restrict__ M, const float* __restrict__ cvec,
    const float* __restrict__ uvec, const float* __restrict__ s0v,
    const float* __restrict__ g_sl, const float* __restrict__ beta_sl,
    float* __restrict__ S_buf, float* __restrict__ qk, float* __restrict__ qb,
    float* __restrict__ acc, float* __restrict__ asum)
{
  __shared__ float vals[64];
  __shared__ float red[4][64];
  int bi = blockIdx.x;
  int tid = threadIdx.x, w = tid >> 6, lane = tid & 63;
  float sl = mu[lane] + __expf(lsig[lane]) * noise[bi * 64 + lane];
  if (w == 0) {
    S_buf[bi * 64 + lane] = sl;
    acc[bi * 64 + lane] = 0.0f;
    if (lane == 0) asum[bi] = 0.0f;
  }
  slot_qk_256(bi, sl, w, lane, M, cvec, uvec, s0v, g_sl, beta_sl, qk, qb, red, vals);
}

// ---------------------------------------------------------------------------
// Main streaming pass. grid = (32 chunks, 64 batches), block = 256.
// Each wave handles 4 rows/iter: lane group (lane>>4) = row, (lane&15)*4 = e.
// All 16-lane reductions are DPP VALU adds (red16) — no LDS-pipe traffic.
__global__ __launch_bounds__(256) void k_main(
    const float* __restrict__ inputs,
    const float* __restrict__ g_in, const float* __restrict__ beta_in,
    const float* __restrict__ qk, const float* __restrict__ qb,
    float* __restrict__ acc, float* __restrict__ asum)
{
  __shared__ float lds_acc[4][512];
  __shared__ float lds_as[4][8];
  const int b = blockIdx.y;
  const int chunk = blockIdx.x;
  const int tid = threadIdx.x;
  const int lane = tid & 63;
  const int wave = tid >> 6;
  const int p = lane & 15;

  float4 g4  = ((const float4*)g_in)[p];
  float4 be4 = ((const float4*)beta_in)[p];
  float4 qkv[8];
  float qbv[8];
  const float4* qk4 = (const float4*)(qk + b * 512);
#pragma unroll
  for (int i = 0; i < 8; ++i) {
    qkv[i] = qk4[i * 16 + p];
    qbv[i] = qb[b * 8 + i];
  }

  float4 accl[8];
  float asl[8];
#pragma unroll
  for (int i = 0; i < 8; ++i) { accl[i] = make_float4(0.f, 0.f, 0.f, 0.f); asl[i] = 0.f; }

  const float4* in4 = (const float4*)(inputs + (size_t)b * 4096 * 64);
  const int n0 = chunk * 128;

  for (int it = 0; it < 8; ++it) {
    int rbase = n0 + it * 16 + wave * 4;  // this wave's 4 rows
    float4 xv = in4[rbase * 16 + lane];

    // LayerNorm stats over the row (64 elems across 16 lanes) — DPP allreduce
    float s  = red16(xv.x + xv.y + xv.z + xv.w);
    float s2 = red16(xv.x * xv.x + xv.y * xv.y + xv.z * xv.z + xv.w * xv.w);
    float mean = s * 0.015625f;
    float var  = s2 * 0.015625f - mean * mean;
    float rstd = rsqrtf(var + LN_EPS);
    float4 xln;
    xln.x = (xv.x - mean) * rstd * g4.x + be4.x;
    xln.y = (xv.y - mean) * rstd * g4.y + be4.y;
    xln.z = (xv.z - mean) * rstd * g4.z + be4.z;
    xln.w = (xv.w - mean) * rstd * g4.w + be4.w;

    // dots vs 8 slots — DPP allreduce per slot
    float dots[8];
#pragma unroll
    for (int i = 0; i < 8; ++i) {
      float d = xln.x * qkv[i].x + xln.y * qkv[i].y + xln.z * qkv[i].z + xln.w * qkv[i].w;
      dots[i] = red16(d) + qbv[i];
    }

    // softmax over slots + eps (replicated across the 16 lanes of the group)
    float mx = dots[0];
#pragma unroll
    for (int i = 1; i < 8; ++i) mx = fmaxf(mx, dots[i]);
    float pv[8];
    float ps = 0.0f;
#pragma unroll
    for (int i = 0; i < 8; ++i) { pv[i] = __expf(dots[i] - mx); ps += pv[i]; }
    float inv = __builtin_amdgcn_rcpf(ps);
#pragma unroll
    for (int i = 0; i < 8; ++i) {
      float pp = pv[i] * inv + EPS_ATTN;
      asl[i] += pp;
      accl[i].x += pp * xln.x;
      accl[i].y += pp * xln.y;
      accl[i].z += pp * xln.z;
      accl[i].w += pp * xln.w;
    }
  }

  // combine the 4 row-groups within the wave (once per block — cheap)
#pragma unroll
  for (int i = 0; i < 8; ++i) {
#pragma unroll
    for (int m = 16; m <= 32; m <<= 1) {
      accl[i].x += __shfl_xor(accl[i].x, m, 64);
      accl[i].y += __shfl_xor(accl[i].y, m, 64);
      accl[i].z += __shfl_xor(accl[i].z, m, 64);
      accl[i].w += __shfl_xor(accl[i].w, m, 64);
      asl[i]    += __shfl_xor(asl[i], m, 64);
    }
  }

  if (lane < 16) {
    float4* dst = (float4*)lds_acc[wave];
#pragma unroll
    for (int i = 0; i < 8; ++i) dst[i * 16 + p] = accl[i];
  }
  if (lane == 0) {
#pragma unroll
    for (int i = 0; i < 8; ++i) lds_as[wave][i] = asl[i];
  }
  __syncthreads();

  for (int f = tid; f < 512; f += 256) {
    float ssum = lds_acc[0][f] + lds_acc[1][f] + lds_acc[2][f] + lds_acc[3][f];
    atomicAdd(&acc[b * 512 + f], ssum);
  }
  if (tid < 8) {
    float ssum = lds_as[0][tid] + lds_as[1][tid] + lds_as[2][tid] + lds_as[3][tid];
    atomicAdd(&asum[b * 8 + tid], ssum);
  }
}

// ---------------------------------------------------------------------------
// Per-slot update with 256 threads / 4-way K-split.
__global__ __launch_bounds__(256) void k_update(
    const float* __restrict__ S_in, float* __restrict__ S_out,
    float* __restrict__ acc, float* __restrict__ asum,
    const float* __restrict__ wv, const float* __restrict__ bv,
    const float* __restrict__ w_ih, const float* __restrict__ b_ih,
    const float* __restrict__ w_hh, const float* __restrict__ b_hh,
    const float* __restrict__ w1, const float* __restrict__ b1,
    const float* __restrict__ w2, const float* __restrict__ b2,
    const float* __restrict__ g_ff, const float* __restrict__ beta_ff,
    const float* __restrict__ M, const float* __restrict__ cvec,
    const float* __restrict__ uvec, const float* __restrict__ s0v,
    const float* __restrict__ g_sl, const float* __restrict__ beta_sl,
    float* __restrict__ qk, float* __restrict__ qb)
{
  __shared__ float vals[128];
  __shared__ float red[6][4][64];
  float* redf = &red[0][0][0];
  int bi = blockIdx.x;
  int tid = threadIdx.x, w = tid >> 6, lane = tid & 63;

  if (tid < 64) {
    float inv = 1.0f / asum[bi];
    vals[tid] = acc[bi * 64 + tid] * inv;
    acc[bi * 64 + tid] = 0.0f;
    if (tid == 0) asum[bi] = 0.0f;
  }
  float sp = S_in[bi * 64 + lane];
  __syncthreads();

  float pu = 0.0f;
#pragma unroll
  for (int j = 0; j < 16; ++j) {
    int e = w * 16 + j;
    pu += vals[e] * wv[e * 64 + lane];
  }
  red[0][w][lane] = pu;
  __syncthreads();
  float upd = bv[lane] + red[0][0][lane] + red[0][1][lane] + red[0][2][lane] + red[0][3][lane];
  __syncthreads();
  if (w == 0) { vals[lane] = upd; vals[64 + lane] = sp; }
  __syncthreads();

  float pr = 0, pz = 0, pn = 0, qr = 0, qz = 0, qn = 0;
#pragma unroll 4
  for (int j = 0; j < 16; ++j) {
    int e = w * 16 + j;
    float uu = vals[e], hh = vals[64 + e];
    const float* wi = w_ih + e * 192;
    const float* wh = w_hh + e * 192;
    pr += uu * wi[lane]; pz += uu * wi[64 + lane]; pn += uu * wi[128 + lane];
    qr += hh * wh[lane]; qz += hh * wh[64 + lane]; qn += hh * wh[128 + lane];
  }
  red[0][w][lane] = pr; red[1][w][lane] = pz; red[2][w][lane] = pn;
  red[3][w][lane] = qr; red[4][w][lane] = qz; red[5][w][lane] = qn;
  __syncthreads();
  float gxr = b_ih[lane], gxz = b_ih[64 + lane], gxn = b_ih[128 + lane];
  float ghr = b_hh[lane], ghz = b_hh[64 + lane], ghn = b_hh[128 + lane];
#pragma unroll
  for (int k = 0; k < 4; ++k) {
    gxr += red[0][k][lane]; gxz += red[1][k][lane]; gxn += red[2][k][lane];
    ghr += red[3][k][lane]; ghz += red[4][k][lane]; ghn += red[5][k][lane];
  }
  float r  = 1.0f / (1.0f + __expf(-(gxr + ghr)));
  float z  = 1.0f / (1.0f + __expf(-(gxz + ghz)));
  float nw = tanhf(gxn + r * ghn);
  float sn = (1.0f - z) * nw + z * sp;

  float s  = wave_reduce_add64(sn);
  float s2 = wave_reduce_add64(sn * sn);
  float mean = s * (1.0f / 64.0f);
  float var  = s2 * (1.0f / 64.0f) - mean * mean;
  float rstd = rsqrtf(var + LN_EPS);
  float ff = (sn - mean) * rstd * g_ff[lane] + beta_ff[lane];
  __syncthreads();
  if (w == 0) vals[lane] = ff;
  __syncthreads();
  {
    int o = tid & 127, half = tid >> 7;
    float ph = 0.0f;
#pragma unroll 8
    for (int j = 0; j < 32; ++j) {
      int e = half * 32 + j;
      ph += vals[e] * w1[e * 128 + o];
    }
    redf[half * 128 + o] = ph;
  }
  __syncthreads();
  if (tid < 128)
    vals[tid] = fmaxf(b1[tid] + redf[tid] + redf[128 + tid], 0.0f);
  __syncthreads();

  float po = 0.0f;
#pragma unroll 8
  for (int j = 0; j < 32; ++j) {
    int t = w * 32 + j;
    po += vals[t] * w2[t * 64 + lane];
  }
  __syncthreads();
  red[0][w][lane] = po;
  __syncthreads();
  float o = sn + b2[lane] + red[0][0][lane] + red[0][1][lane] + red[0][2][lane] + red[0][3][lane];
  if (w == 0) S_out[bi * 64 + lane] = o;

  slot_qk_256(bi, o, w, lane, M, cvec, uvec, s0v, g_sl, beta_sl, qk, qb,
              (float(*)[64])redf, vals);
}

// ---------------------------------------------------------------------------
extern "C" void kernel_launch(void* const* d_in, const int* in_sizes, int n_in,
                              void* d_out, int out_size, void* d_ws, size_t ws_size,
                              hipStream_t stream) {
  const float* inputs  = (const float*)d_in[0];
  const float* noise   = (const float*)d_in[1];
  const float* mu      = (const float*)d_in[2];
  const float* lsig    = (const float*)d_in[3];
  const float* wq      = (const float*)d_in[4];
  const float* bq      = (const float*)d_in[5];
  const float* wk      = (const float*)d_in[6];
  const float* bk      = (const float*)d_in[7];
  const float* wv      = (const float*)d_in[8];
  const float* bv      = (const float*)d_in[9];
  const float* w_ih    = (const float*)d_in[10];
  const float* b_ih    = (const float*)d_in[11];
  const float* w_hh    = (const float*)d_in[12];
  const float* b_hh    = (const float*)d_in[13];
  const float* w1      = (const float*)d_in[14];
  const float* b1      = (const float*)d_in[15];
  const float* w2      = (const float*)d_in[16];
  const float* b2      = (const float*)d_in[17];
  const float* g_in    = (const float*)d_in[18];
  const float* beta_in = (const float*)d_in[19];
  const float* g_sl    = (const float*)d_in[20];
  const float* beta_sl = (const float*)d_in[21];
  const float* g_ff    = (const float*)d_in[22];
  const float* beta_ff = (const float*)d_in[23];

  float* S_buf = (float*)d_ws;        // [64*8*64]
  float* qk    = S_buf + 32768;       // [64*8*64]
  float* qb    = qk + 32768;          // [64*8]
  float* acc   = qb + 512;            // [64*8*64]
  float* asum  = acc + 32768;         // [64*8]
  float* M     = asum + 512;          // [64*64]
  float* cvec  = M + 4096;            // [64]
  float* uvec  = cvec + 64;           // [64]
  float* s0v   = uvec + 64;           // [1]
  float* out   = (float*)d_out;

  k_prep<<<16, 256, 0, stream>>>(wq, wk, bq, bk, M, cvec, uvec, s0v);
  k_init<<<512, 256, 0, stream>>>(noise, mu, lsig, M, cvec, uvec, s0v,
                                  g_sl, beta_sl, S_buf, qk, qb, acc, asum);

  for (int t = 0; t < 3; ++t) {
    k_main<<<dim3(32, 64), 256, 0, stream>>>(inputs, g_in, beta_in, qk, qb, acc, asum);
    float* dst = (t == 2) ? out : S_buf;
    k_update<<<512, 256, 0, stream>>>(S_buf, dst, acc, asum, wv, bv,
                                      w_ih, b_ih, w_hh, b_hh, w1, b1, w2, b2,
                                      g_ff, beta_ff, M, cvec, uvec, s0v,
                                      g_sl, beta_sl, qk, qb);
  }
}